// Round 11
// baseline (408.716 us; speedup 1.0000x reference)
//
#include <hip/hip_runtime.h>
#include <stdint.h>

#define B_BATCH 64
#define L_SEQ 2048
#define E_DIM 1024
#define A_DIM 512

typedef __attribute__((ext_vector_type(4))) float f32x4;
typedef __attribute__((ext_vector_type(8))) short bf16x8;
typedef __attribute__((ext_vector_type(2))) unsigned int u32x2;
typedef __attribute__((ext_vector_type(4))) unsigned int u32x4;

__device__ __forceinline__ unsigned short f2bf(float f) {
  unsigned u = __float_as_uint(f);
  u = (u + 0x7fffu + ((u >> 16) & 1u)) >> 16;  // RNE
  return (unsigned short)u;
}

__device__ __forceinline__ u32x2 packbf(f32x4 v) {
  u32x2 r;
  r.x = (unsigned)f2bf(v.x) | ((unsigned)f2bf(v.y) << 16);
  r.y = (unsigned)f2bf(v.z) | ((unsigned)f2bf(v.w) << 16);
  return r;
}

// A-LDS chunk (32-k x 64 rows): 64 B rows, 16B slot s of row n at s ^ ((n>>1)&3);
// slot g holds k {4g..4g+3} (low 8B) and {16+4g..16+4g+3} (high 8B). Proven R1-R10.
// BK=64 buffer = 2 chunks = 8 KB; double-buffered = 16 KB -> 2 blocks/CU fit easily.
#define CHUNKB 4096
#define ABUF (2 * CHUNKB)
#define BCHUNK 32768         // ws_B bytes per 32-k chunk (512 cols x 64 B frags)
#define BCOPY (32 * BCHUNK)  // 1 MB per XCD copy

// ---------------- K0: We_w (fp32 [1024,512]) -> ws_B bf16 frag image, replicated x8 --------
__global__ void prep_we_kernel(const float* __restrict__ We, char* __restrict__ wsB) {
  int t = blockIdx.x * 256 + threadIdx.x;  // 65536 threads = 1 16B chunk each
  int lane = t & 63;
  int colblk = (t >> 6) & 31;
  int step = t >> 11;  // 0..31
  int nl = lane & 15, g = lane >> 4;
  int col = colblk * 16 + nl;
  int k0 = step * 32 + 4 * g;
  unsigned q0 = (unsigned)f2bf(We[(size_t)(k0 + 0) * A_DIM + col]) |
                ((unsigned)f2bf(We[(size_t)(k0 + 1) * A_DIM + col]) << 16);
  unsigned q1 = (unsigned)f2bf(We[(size_t)(k0 + 2) * A_DIM + col]) |
                ((unsigned)f2bf(We[(size_t)(k0 + 3) * A_DIM + col]) << 16);
  unsigned q2 = (unsigned)f2bf(We[(size_t)(k0 + 16) * A_DIM + col]) |
                ((unsigned)f2bf(We[(size_t)(k0 + 17) * A_DIM + col]) << 16);
  unsigned q3 = (unsigned)f2bf(We[(size_t)(k0 + 18) * A_DIM + col]) |
                ((unsigned)f2bf(We[(size_t)(k0 + 19) * A_DIM + col]) << 16);
  u32x4 v; v.x = q0; v.y = q1; v.z = q2; v.w = q3;
#pragma unroll
  for (int c = 0; c < 8; ++c)
    *(u32x4*)(wsB + (size_t)c * BCOPY + (size_t)t * 16) = v;
}

// ---------------- K1: dcomb[b][a] = decoder_hidden[b]·Wd_w[:,a] + Wd_b[a] + We_b[a] --------
__global__ void dec_comb_kernel(const float* __restrict__ dh, const float* __restrict__ Wd,
                                const float* __restrict__ Wdb, const float* __restrict__ Web,
                                float* __restrict__ dcomb) {
  __shared__ float sh[1024];
  const int b = blockIdx.x, tid = threadIdx.x;
  for (int i = tid; i < 1024; i += 128) sh[i] = dh[b * 1024 + i];
  __syncthreads();
  const int a = blockIdx.y * 128 + tid;
  float acc = Wdb[a] + Web[a];
#pragma unroll 4
  for (int e = 0; e < 1024; ++e) acc += sh[e] * Wd[(size_t)e * A_DIM + a];
  dcomb[b * A_DIM + a] = acc;
}

// ---------------- K2: fused score GEMM — occupancy-first (2 independent blocks/CU) --------
// block: 64 rows x 512 cols, 8 waves (512 thr), wave = 64x64 -> acc[4][4] = 64 VGPR.
// __launch_bounds__(512,4): 4 waves/SIMD = 2 blocks/CU; VGPR capped at 128.
// Plain double-buffered LDS for A (BK=64, 16 iters, one __syncthreads per iter);
// B register-direct from XCD-local L2 copy. NO manual waitcnt — cross-block TLP
// (m114) covers barrier drains and load latency.
__global__ __launch_bounds__(512, 4) void score_gemm_kernel(
    const float* __restrict__ enc, const char* __restrict__ wsB,
    const float* __restrict__ dcomb, const float* __restrict__ wf,
    float* __restrict__ scoreOut) {
  __shared__ __align__(16) char smem[2 * ABUF];
  __shared__ float s_score[64];

  const int tid = threadIdx.x;
  const int lane = tid & 63;
  const int w = tid >> 6;      // 0..7 -> cols w*64..w*64+63
  const int g = lane >> 4;
  const int nl = lane & 15;
  const int gs = g ^ ((nl >> 1) & 3);

  const int row0 = (int)blockIdx.x * 64;
  const int bb = row0 >> 11;

  if (tid < 64) s_score[tid] = 0.0f;

  const float* encA = enc + (size_t)row0 * E_DIM;

  int aoff[4];
#pragma unroll
  for (int rt = 0; rt < 4; ++rt) aoff[rt] = (rt * 16 + nl) * 64 + gs * 16;

  // A staging: thread -> row ar = tid>>3 (0..63), k-oct ac = tid&7.
  // Per iter t: L0 = 16B at k = t*64 + ac*4 (chunk0), L1 = +32 k (chunk1).
  // 8 threads/row cover 256 B contiguous per row per iter.
  const int ar = tid >> 3, ac = tid & 7;
  const float* asrc = encA + (size_t)ar * E_DIM + ac * 4;
  const int slot = (ac & 3) ^ ((ar >> 1) & 3);
  const int aw0 = ar * 64 + slot * 16 + (ac >> 2) * 8;   // chunk0
  const int aw1 = aw0 + CHUNKB;                          // chunk1

  // B frags: wave w reads col-blocks w*4+ct of each 32-k chunk from local-XCD copy
  const char* bsrc = wsB + (size_t)(blockIdx.x & 7) * BCOPY + (w * 4) * 1024 + lane * 16;

  f32x4 acc[4][4];
#pragma unroll
  for (int rt = 0; rt < 4; ++rt)
#pragma unroll
    for (int ct = 0; ct < 4; ++ct) {
      f32x4 z = {0.f, 0.f, 0.f, 0.f};
      acc[rt][ct] = z;
    }

  // prologue: stage iter-0 A into buf0
  {
    f32x4 L0 = *(const f32x4*)(asrc);
    f32x4 L1 = *(const f32x4*)(asrc + 32);
    *(u32x2*)(smem + aw0) = packbf(L0);
    *(u32x2*)(smem + aw1) = packbf(L1);
  }
  __syncthreads();

#pragma unroll 1
  for (int t = 0; t < 16; ++t) {
    const int cur = (t & 1) * ABUF;
    const int nxt = cur ^ ABUF;
    f32x4 L0, L1;
    if (t < 15) {
      L0 = *(const f32x4*)(asrc + (size_t)(t + 1) * 64);
      L1 = *(const f32x4*)(asrc + (size_t)(t + 1) * 64 + 32);
    }
    // chunk 0
    {
      bf16x8 bfr[4], afr[4];
#pragma unroll
      for (int ct = 0; ct < 4; ++ct)
        bfr[ct] = *(const bf16x8*)(bsrc + (size_t)(2 * t) * BCHUNK + ct * 1024);
#pragma unroll
      for (int rt = 0; rt < 4; ++rt)
        afr[rt] = *(const bf16x8*)(smem + cur + aoff[rt]);
#pragma unroll
      for (int rt = 0; rt < 4; ++rt)
#pragma unroll
        for (int ct = 0; ct < 4; ++ct)
          acc[rt][ct] = __builtin_amdgcn_mfma_f32_16x16x32_bf16(afr[rt], bfr[ct],
                                                                acc[rt][ct], 0, 0, 0);
    }
    // chunk 1
    {
      bf16x8 bfr[4], afr[4];
#pragma unroll
      for (int ct = 0; ct < 4; ++ct)
        bfr[ct] = *(const bf16x8*)(bsrc + (size_t)(2 * t + 1) * BCHUNK + ct * 1024);
#pragma unroll
      for (int rt = 0; rt < 4; ++rt)
        afr[rt] = *(const bf16x8*)(smem + cur + CHUNKB + aoff[rt]);
#pragma unroll
      for (int rt = 0; rt < 4; ++rt)
#pragma unroll
        for (int ct = 0; ct < 4; ++ct)
          acc[rt][ct] = __builtin_amdgcn_mfma_f32_16x16x32_bf16(afr[rt], bfr[ct],
                                                                acc[rt][ct], 0, 0, 0);
    }
    if (t < 15) {
      *(u32x2*)(smem + nxt + aw0) = packbf(L0);
      *(u32x2*)(smem + nxt + aw1) = packbf(L1);
    }
    __syncthreads();
  }

  // epilogue: h = relu(acc + db), p = h·wf, reduce over 512 cols
  float db[4], wv[4];
#pragma unroll
  for (int ct = 0; ct < 4; ++ct) {
    int a = w * 64 + ct * 16 + nl;
    db[ct] = dcomb[bb * A_DIM + a];
    wv[ct] = wf[a];
  }
#pragma unroll
  for (int rt = 0; rt < 4; ++rt) {
#pragma unroll
    for (int r = 0; r < 4; ++r) {
      float p = 0.f;
#pragma unroll
      for (int ct = 0; ct < 4; ++ct) {
        float h = acc[rt][ct][r] + db[ct];
        h = h > 0.f ? h : 0.f;
        p += h * wv[ct];
      }
      p += __shfl_xor(p, 1);
      p += __shfl_xor(p, 2);
      p += __shfl_xor(p, 4);
      p += __shfl_xor(p, 8);
      if (nl == 0) atomicAdd(&s_score[rt * 16 + g * 4 + r], p);
    }
  }
  __syncthreads();
  if (tid < 64) scoreOut[row0 + tid] = s_score[tid];
}

// ---------------- K3: softmax over L per batch, in place -----------------------------------
__global__ void softmax_kernel(float* __restrict__ attn) {
  __shared__ float red[8];
  const int b = blockIdx.x, tid = threadIdx.x;
  float* p = attn + b * L_SEQ;
  float v[8];
  float m = -1e30f;
#pragma unroll
  for (int i = 0; i < 8; ++i) {
    v[i] = p[tid + i * 256];
    m = fmaxf(m, v[i]);
  }
#pragma unroll
  for (int off = 1; off < 64; off <<= 1) m = fmaxf(m, __shfl_xor(m, off));
  const int wid = tid >> 6;
  if ((tid & 63) == 0) red[wid] = m;
  __syncthreads();
  m = fmaxf(fmaxf(red[0], red[1]), fmaxf(red[2], red[3]));
  float s = 0.f;
#pragma unroll
  for (int i = 0; i < 8; ++i) {
    v[i] = __expf(v[i] - m);
    s += v[i];
  }
#pragma unroll
  for (int off = 1; off < 64; off <<= 1) s += __shfl_xor(s, off);
  __syncthreads();
  if ((tid & 63) == 0) red[4 + wid] = s;
  __syncthreads();
  const float inv = 1.0f / (red[4] + red[5] + red[6] + red[7]);
#pragma unroll
  for (int i = 0; i < 8; ++i) p[tid + i * 256] = v[i] * inv;
}

// ---------------- K4a: weighted stage 1 — private partials, zero atomics -------------------
__global__ void weighted_part_kernel(const float* __restrict__ enc,
                                     const float* __restrict__ alpha,
                                     float* __restrict__ part) {
  __shared__ float sa[64];
  const int bid = blockIdx.x;  // 2048 = 64 b * 32 l-segments of 64
  const int b = bid >> 5, ls = bid & 31;
  const int tid = threadIdx.x;
  if (tid < 64) sa[tid] = alpha[b * L_SEQ + ls * 64 + tid];
  __syncthreads();
  const float* base = enc + ((size_t)(b * L_SEQ + ls * 64)) * E_DIM;
  f32x4 acc = {0.f, 0.f, 0.f, 0.f};
#pragma unroll 8
  for (int il = 0; il < 64; ++il) {
    f32x4 v = *(const f32x4*)(base + (size_t)il * E_DIM + tid * 4);
    float al = sa[il];
    acc.x += al * v.x;
    acc.y += al * v.y;
    acc.z += al * v.z;
    acc.w += al * v.w;
  }
  *(f32x4*)(part + (size_t)bid * E_DIM + tid * 4) = acc;
}

// ---------------- K4b: weighted stage 2 — sum 32 partials per batch ------------------------
__global__ void weighted_reduce_kernel(const float* __restrict__ part,
                                       float* __restrict__ outW) {
  const int b = blockIdx.x, tid = threadIdx.x;
  const float* p = part + (size_t)b * 32 * E_DIM + tid * 4;
  f32x4 acc = {0.f, 0.f, 0.f, 0.f};
#pragma unroll 8
  for (int ls = 0; ls < 32; ++ls) {
    f32x4 v = *(const f32x4*)(p + (size_t)ls * E_DIM);
    acc.x += v.x;
    acc.y += v.y;
    acc.z += v.z;
    acc.w += v.w;
  }
  *(f32x4*)(outW + (size_t)b * E_DIM + tid * 4) = acc;
}

extern "C" void kernel_launch(void* const* d_in, const int* in_sizes, int n_in,
                              void* d_out, int out_size, void* d_ws, size_t ws_size,
                              hipStream_t stream) {
  const float* enc = (const float*)d_in[0];
  const float* dh = (const float*)d_in[1];
  const float* WeW = (const float*)d_in[2];
  const float* WeB = (const float*)d_in[3];
  const float* WdW = (const float*)d_in[4];
  const float* WdB = (const float*)d_in[5];
  const float* WfW = (const float*)d_in[6];
  // Wf_b (d_in[7]) irrelevant: softmax is shift-invariant and attn isn't an output.

  float* out = (float*)d_out;
  float* outW = out;                      // weighted: 64*1024
  float* attn = out + B_BATCH * E_DIM;    // scores -> alpha: 64*2048

  char* wsB = (char*)d_ws;                                    // 8 copies x 1 MB
  float* dcomb = (float*)((char*)d_ws + 8 * (size_t)BCOPY);   // 64*512 fp32 (128 KB)
  float* part = (float*)((char*)d_ws + 8 * (size_t)BCOPY +
                         (size_t)B_BATCH * A_DIM * sizeof(float));  // 8 MB partials

  const size_t need = 8 * (size_t)BCOPY + (size_t)B_BATCH * A_DIM * sizeof(float) +
                      (size_t)B_BATCH * 32 * E_DIM * sizeof(float);
  if (ws_size < need) return;

  prep_we_kernel<<<256, 256, 0, stream>>>(WeW, wsB);
  dec_comb_kernel<<<dim3(B_BATCH, 4), 128, 0, stream>>>(dh, WdW, WdB, WeB, dcomb);
  score_gemm_kernel<<<(B_BATCH * L_SEQ) / 64, 512, 0, stream>>>(enc, wsB, dcomb, WfW, attn);
  softmax_kernel<<<B_BATCH, 256, 0, stream>>>(attn);
  weighted_part_kernel<<<B_BATCH * 32, 256, 0, stream>>>(enc, attn, part);
  weighted_reduce_kernel<<<B_BATCH, 256, 0, stream>>>(part, outW);
}